// Round 7
// baseline (538.930 us; speedup 1.0000x reference)
//
#include <hip/hip_runtime.h>
#include <math.h>

#define IN_DIM 300
#define MEM 256
#define DEPTH 15
#define NNODES ((1 << (DEPTH + 1)) - 1)   // 65535
#define KX 320     // x-GEMM K (300 padded)
#define KH 256     // h-GEMM K
#define NKX 10     // KX/32
#define NKH 8      // KH/32
#define SX 328     // LDS row stride bf16
#define SH 264     // LDS row stride bf16
#define NT 32      // nodes per tile (2 x 16-row MFMA sub-tiles)
#define RSTR 41    // reduce-buffer lane stride f32 (odd -> conflict-free)
#define XPRE_NODES 8191   // nodes 0..8190 = levels d <= 12

typedef __attribute__((ext_vector_type(8))) __bf16 bf16x8;
typedef __attribute__((ext_vector_type(4))) float f32x4;

__device__ __forceinline__ float sigmoidf_(float x) { return 1.0f / (1.0f + __expf(-x)); }
__device__ __forceinline__ float tanhfast_(float x) {
    return 1.0f - 2.0f / (__expf(2.0f * x) + 1.0f);
}
__device__ __forceinline__ f32x4 mfma_bf16(bf16x8 a, bf16x8 b, f32x4 acc) {
    return __builtin_amdgcn_mfma_f32_16x16x32_bf16(a, b, acc, 0, 0, 0);
}

// Fragment-linear B layout: elem(cb, ks, lane, e) at ((cb*NK + ks)*64 + lane)*8 + e,
// holding W[col = cb*16 + (lane&15)][k = ks*32 + (lane>>4)*8 + e].
#define WTXF_ELEMS (64 * NKX * 512)   // 327680  (cols 0..767 = W_ioux, 768..1023 = W_fx)
#define WTHF_ELEMS (64 * NKH * 512)   // 262144  (cols 0..767 = W_iouh, 768..1023 = W_fh)

__global__ void prep_weights(const float* __restrict__ W_ioux, const float* __restrict__ W_fx,
                             const float* __restrict__ W_iouh, const float* __restrict__ W_fh,
                             __bf16* __restrict__ ws) {
    int idx = blockIdx.x * 256 + threadIdx.x;
    if (idx < WTXF_ELEMS) {
        int e = idx & 7, ln = (idx >> 3) & 63;
        int r = idx >> 9;             // 0..639
        int ks = r % NKX, cb = r / NKX;
        int col = cb * 16 + (ln & 15);
        int k = ks * 32 + (ln >> 4) * 8 + e;
        float v = 0.f;
        if (k < IN_DIM)
            v = (col < 768) ? W_ioux[col * IN_DIM + k] : W_fx[(col - 768) * IN_DIM + k];
        ws[idx] = (__bf16)v;
    } else if (idx < WTXF_ELEMS + WTHF_ELEMS) {
        int t = idx - WTXF_ELEMS;
        int e = t & 7, ln = (t >> 3) & 63;
        int r = t >> 9;               // 0..511
        int ks = r & 7, cb = r >> 3;
        int col = cb * 16 + (ln & 15);
        int k = ks * 32 + (ln >> 4) * 8 + e;
        float v = (col < 768) ? W_iouh[col * MEM + k] : W_fh[(col - 768) * MEM + k];
        ws[WTXF_ELEMS + t] = (__bf16)v;
    }
}

// ---- shared staging helpers (512 threads) ----
__device__ __forceinline__ void stage_x(const float* __restrict__ x_in, __bf16* Xs,
                                        int node0, int mcount) {
    for (int t = threadIdx.x; t < NT * (KX / 8); t += 512) {
        int m = t / (KX / 8), kc = t - m * (KX / 8), k = kc * 8;
        float4 v0 = {0.f, 0.f, 0.f, 0.f}, v1 = {0.f, 0.f, 0.f, 0.f};
        if (m < mcount) {
            const float* row = x_in + (size_t)(node0 + m) * IN_DIM;
            if (k + 8 <= IN_DIM) { v0 = *(const float4*)(row + k); v1 = *(const float4*)(row + k + 4); }
            else if (k == 296)   { v0 = *(const float4*)(row + k); }   // 296..299 valid
        }
        bf16x8 pk;
        pk[0] = (__bf16)v0.x; pk[1] = (__bf16)v0.y; pk[2] = (__bf16)v0.z; pk[3] = (__bf16)v0.w;
        pk[4] = (__bf16)v1.x; pk[5] = (__bf16)v1.y; pk[6] = (__bf16)v1.z; pk[7] = (__bf16)v1.w;
        *(bf16x8*)&Xs[m * SX + k] = pk;
    }
}

__device__ __forceinline__ void stage_h(const float* __restrict__ h, __bf16* Hlr, __bf16* Hsum,
                                        int childbase, int mcount) {
    for (int t = threadIdx.x; t < NT * (KH / 8); t += 512) {
        int m = t >> 5, kc = t & 31, k = kc * 8;
        float4 l0 = {0.f,0.f,0.f,0.f}, l1 = l0, r0 = l0, r1 = l0;
        if (m < mcount) {
            const float4* lp = (const float4*)(h + (size_t)(childbase + 2 * m) * MEM + k);
            const float4* rp = (const float4*)(h + (size_t)(childbase + 2 * m + 1) * MEM + k);
            l0 = lp[0]; l1 = lp[1]; r0 = rp[0]; r1 = rp[1];
        }
        bf16x8 pl, pr, ps;
        pl[0]=(__bf16)l0.x; pl[1]=(__bf16)l0.y; pl[2]=(__bf16)l0.z; pl[3]=(__bf16)l0.w;
        pl[4]=(__bf16)l1.x; pl[5]=(__bf16)l1.y; pl[6]=(__bf16)l1.z; pl[7]=(__bf16)l1.w;
        pr[0]=(__bf16)r0.x; pr[1]=(__bf16)r0.y; pr[2]=(__bf16)r0.z; pr[3]=(__bf16)r0.w;
        pr[4]=(__bf16)r1.x; pr[5]=(__bf16)r1.y; pr[6]=(__bf16)r1.z; pr[7]=(__bf16)r1.w;
        ps[0]=(__bf16)(l0.x+r0.x); ps[1]=(__bf16)(l0.y+r0.y);
        ps[2]=(__bf16)(l0.z+r0.z); ps[3]=(__bf16)(l0.w+r0.w);
        ps[4]=(__bf16)(l1.x+r1.x); ps[5]=(__bf16)(l1.y+r1.y);
        ps[6]=(__bf16)(l1.z+r1.z); ps[7]=(__bf16)(l1.w+r1.w);
        *(bf16x8*)&Hlr[m * SH + k] = pl;
        *(bf16x8*)&Hlr[(NT + m) * SH + k] = pr;
        *(bf16x8*)&Hsum[m * SH + k] = ps;
    }
}

// 512-thread / 8-wave tile. Wave w owns TWO 16-col slices (s0=2w, s1=2w+1) of
// every gate group -> 8 B-streams, acc = 80 f32. 8-wave block = 2 waves/SIMD
// -> 256-reg budget: no spill (16-wave blocks cap at 128 regs and spilled).
template <bool LEAF>
__device__ __forceinline__ void tile_body(
    const float* __restrict__ x_in,
    const __bf16* __restrict__ wtx, const __bf16* __restrict__ wth,
    const float* __restrict__ b_ioux, const float* __restrict__ b_iouh,
    const float* __restrict__ b_fx, const float* __restrict__ b_fh,
    float* __restrict__ c, float* __restrict__ h,
    int node0, int mcount, __bf16* Xs, __bf16* Hlr, __bf16* Hsum)
{
    const int tid = threadIdx.x;               // 0..511
    const int w = tid >> 6, l = tid & 63, lc = l & 15, q = l >> 4;
    const int childbase = 2 * node0 + 1;

    stage_x(x_in, Xs, node0, mcount);
    if constexpr (!LEAF) stage_h(h, Hlr, Hsum, childbase, mcount);
    __syncthreads();

    const f32x4 z4 = {0.f, 0.f, 0.f, 0.f};
    f32x4 aI[2][2], aO[2][2], aU[2][2], aL[2][2], aR[2][2];
#pragma unroll
    for (int s = 0; s < 2; ++s)
#pragma unroll
        for (int mt = 0; mt < 2; ++mt) {
            aI[s][mt] = z4; aO[s][mt] = z4; aU[s][mt] = z4;
            if constexpr (!LEAF) { aL[s][mt] = z4; aR[s][mt] = z4; }
        }

    const int s0 = 2 * w, s1 = 2 * w + 1;

    if constexpr (!LEAF) {
        const __bf16* pi0 = wth + ((size_t)(s0)      * NKH) * 512 + l * 8;
        const __bf16* pi1 = wth + ((size_t)(s1)      * NKH) * 512 + l * 8;
        const __bf16* po0 = wth + ((size_t)(16 + s0) * NKH) * 512 + l * 8;
        const __bf16* po1 = wth + ((size_t)(16 + s1) * NKH) * 512 + l * 8;
        const __bf16* pu0 = wth + ((size_t)(32 + s0) * NKH) * 512 + l * 8;
        const __bf16* pu1 = wth + ((size_t)(32 + s1) * NKH) * 512 + l * 8;
        const __bf16* pf0 = wth + ((size_t)(48 + s0) * NKH) * 512 + l * 8;
        const __bf16* pf1 = wth + ((size_t)(48 + s1) * NKH) * 512 + l * 8;
        for (int ks = 0; ks < NKH; ++ks) {
            bf16x8 vi0 = *(const bf16x8*)(pi0 + ks * 512);
            bf16x8 vi1 = *(const bf16x8*)(pi1 + ks * 512);
            bf16x8 vo0 = *(const bf16x8*)(po0 + ks * 512);
            bf16x8 vo1 = *(const bf16x8*)(po1 + ks * 512);
            bf16x8 vu0 = *(const bf16x8*)(pu0 + ks * 512);
            bf16x8 vu1 = *(const bf16x8*)(pu1 + ks * 512);
            bf16x8 vf0 = *(const bf16x8*)(pf0 + ks * 512);
            bf16x8 vf1 = *(const bf16x8*)(pf1 + ks * 512);
            const int ko = ks * 32 + q * 8;
#pragma unroll
            for (int mt = 0; mt < 2; ++mt) {
                bf16x8 as = *(const bf16x8*)&Hsum[(mt * 16 + lc) * SH + ko];
                bf16x8 al = *(const bf16x8*)&Hlr[(mt * 16 + lc) * SH + ko];
                bf16x8 ar = *(const bf16x8*)&Hlr[(NT + mt * 16 + lc) * SH + ko];
                aI[0][mt] = mfma_bf16(as, vi0, aI[0][mt]);
                aI[1][mt] = mfma_bf16(as, vi1, aI[1][mt]);
                aO[0][mt] = mfma_bf16(as, vo0, aO[0][mt]);
                aO[1][mt] = mfma_bf16(as, vo1, aO[1][mt]);
                aU[0][mt] = mfma_bf16(as, vu0, aU[0][mt]);
                aU[1][mt] = mfma_bf16(as, vu1, aU[1][mt]);
                aL[0][mt] = mfma_bf16(al, vf0, aL[0][mt]);
                aL[1][mt] = mfma_bf16(al, vf1, aL[1][mt]);
                aR[0][mt] = mfma_bf16(ar, vf0, aR[0][mt]);
                aR[1][mt] = mfma_bf16(ar, vf1, aR[1][mt]);
            }
        }
    }

    {
        const __bf16* pi0 = wtx + ((size_t)(s0)      * NKX) * 512 + l * 8;
        const __bf16* pi1 = wtx + ((size_t)(s1)      * NKX) * 512 + l * 8;
        const __bf16* po0 = wtx + ((size_t)(16 + s0) * NKX) * 512 + l * 8;
        const __bf16* po1 = wtx + ((size_t)(16 + s1) * NKX) * 512 + l * 8;
        const __bf16* pu0 = wtx + ((size_t)(32 + s0) * NKX) * 512 + l * 8;
        const __bf16* pu1 = wtx + ((size_t)(32 + s1) * NKX) * 512 + l * 8;
        const __bf16* pf0 = wtx + ((size_t)(48 + s0) * NKX) * 512 + l * 8;
        const __bf16* pf1 = wtx + ((size_t)(48 + s1) * NKX) * 512 + l * 8;
        for (int ks = 0; ks < NKX; ++ks) {
            bf16x8 vi0 = *(const bf16x8*)(pi0 + ks * 512);
            bf16x8 vi1 = *(const bf16x8*)(pi1 + ks * 512);
            bf16x8 vo0 = *(const bf16x8*)(po0 + ks * 512);
            bf16x8 vo1 = *(const bf16x8*)(po1 + ks * 512);
            bf16x8 vu0 = *(const bf16x8*)(pu0 + ks * 512);
            bf16x8 vu1 = *(const bf16x8*)(pu1 + ks * 512);
            bf16x8 vf0, vf1;
            if constexpr (!LEAF) {
                vf0 = *(const bf16x8*)(pf0 + ks * 512);
                vf1 = *(const bf16x8*)(pf1 + ks * 512);
            }
            const int ko = ks * 32 + q * 8;
#pragma unroll
            for (int mt = 0; mt < 2; ++mt) {
                bf16x8 ax = *(const bf16x8*)&Xs[(mt * 16 + lc) * SX + ko];
                aI[0][mt] = mfma_bf16(ax, vi0, aI[0][mt]);
                aI[1][mt] = mfma_bf16(ax, vi1, aI[1][mt]);
                aO[0][mt] = mfma_bf16(ax, vo0, aO[0][mt]);
                aO[1][mt] = mfma_bf16(ax, vo1, aO[1][mt]);
                aU[0][mt] = mfma_bf16(ax, vu0, aU[0][mt]);
                aU[1][mt] = mfma_bf16(ax, vu1, aU[1][mt]);
                if constexpr (!LEAF) {
                    aL[0][mt] = mfma_bf16(ax, vf0, aL[0][mt]);
                    aR[0][mt] = mfma_bf16(ax, vf0, aR[0][mt]);
                    aL[1][mt] = mfma_bf16(ax, vf1, aL[1][mt]);
                    aR[1][mt] = mfma_bf16(ax, vf1, aR[1][mt]);
                }
            }
        }
    }

#pragma unroll
    for (int s = 0; s < 2; ++s) {
        const int jj = (2 * w + s) * 16 + lc;
        const float bi = b_ioux[jj]       + b_iouh[jj];
        const float bo = b_ioux[256 + jj] + b_iouh[256 + jj];
        const float bu = b_ioux[512 + jj] + b_iouh[512 + jj];
        float bff = 0.f;
        if constexpr (!LEAF) bff = b_fx[jj] + b_fh[jj];
#pragma unroll
        for (int mt = 0; mt < 2; ++mt) {
#pragma unroll
            for (int r = 0; r < 4; ++r) {
                const int n = mt * 16 + q * 4 + r;
                const float iv = sigmoidf_(aI[s][mt][r] + bi);
                const float ov = sigmoidf_(aO[s][mt][r] + bo);
                const float uv = tanhfast_(aU[s][mt][r] + bu);
                float cn;
                if constexpr (!LEAF) {
                    const float fl = sigmoidf_(aL[s][mt][r] + bff);
                    const float fr = sigmoidf_(aR[s][mt][r] + bff);
                    float cl = 0.f, cr = 0.f;
                    if (n < mcount) {
                        cl = c[(size_t)(childbase + 2 * n) * MEM + jj];
                        cr = c[(size_t)(childbase + 2 * n + 1) * MEM + jj];
                    }
                    cn = iv * uv + fl * cl + fr * cr;
                } else {
                    cn = iv * uv;
                }
                const float hn = ov * tanhfast_(cn);
                if (n < mcount) {
                    c[(size_t)(node0 + n) * MEM + jj] = cn;
                    h[(size_t)(node0 + n) * MEM + jj] = hn;
                }
            }
        }
    }
}

template <bool LEAF, int MINW>
__global__ __launch_bounds__(512, MINW) void level_mfma(
    const float* __restrict__ x_in,
    const __bf16* __restrict__ wtx, const __bf16* __restrict__ wth,
    const float* __restrict__ b_ioux, const float* __restrict__ b_iouh,
    const float* __restrict__ b_fx, const float* __restrict__ b_fh,
    float* __restrict__ c, float* __restrict__ h,
    int start, int levsize)
{
    __shared__ __align__(16) __bf16 Xs[NT * SX];
    __shared__ __align__(16) __bf16 Hlr[LEAF ? 8 : 2 * NT * SH];
    __shared__ __align__(16) __bf16 Hsum[LEAF ? 8 : NT * SH];
    const int tile0 = blockIdx.x * NT;
    tile_body<LEAF>(x_in, wtx, wth, b_ioux, b_iouh, b_fx, b_fh, c, h,
                    start + tile0, min(NT, levsize - tile0), Xs, Hlr, Hsum);
}

// Upfront x-path GEMM for nodes 0..nnodes-1 (tree-independent): writes
// xp[node][1024] = {iou_x + b_ioux + b_iouh (cols 0..767), fx + b_fx + b_fh
// (cols 768..1023)} in f32. Small levels then skip the x-GEMM entirely.
__global__ __launch_bounds__(512, 2) void xpre_gemm(
    const float* __restrict__ x_in, const __bf16* __restrict__ wtx,
    const float* __restrict__ b_ioux, const float* __restrict__ b_iouh,
    const float* __restrict__ b_fx, const float* __restrict__ b_fh,
    float* __restrict__ xp, int nnodes)
{
    __shared__ __align__(16) __bf16 Xs[NT * SX];
    const int tid = threadIdx.x;
    const int w = tid >> 6, l = tid & 63, lc = l & 15, q = l >> 4;
    const int node0 = blockIdx.x * NT;
    const int mcount = min(NT, nnodes - node0);
    stage_x(x_in, Xs, node0, mcount);
    __syncthreads();

    const f32x4 z4 = {0.f, 0.f, 0.f, 0.f};
    f32x4 acc[2][4][2];
#pragma unroll
    for (int sl = 0; sl < 2; ++sl)
#pragma unroll
        for (int g = 0; g < 4; ++g)
#pragma unroll
            for (int mt = 0; mt < 2; ++mt) acc[sl][g][mt] = z4;

    const __bf16* p[2][4];
#pragma unroll
    for (int sl = 0; sl < 2; ++sl) {
        const int s_ = 2 * w + sl;
        p[sl][0] = wtx + ((size_t)(s_)      * NKX) * 512 + l * 8;
        p[sl][1] = wtx + ((size_t)(16 + s_) * NKX) * 512 + l * 8;
        p[sl][2] = wtx + ((size_t)(32 + s_) * NKX) * 512 + l * 8;
        p[sl][3] = wtx + ((size_t)(48 + s_) * NKX) * 512 + l * 8;
    }
    for (int ks = 0; ks < NKX; ++ks) {
        bf16x8 vb[2][4];
#pragma unroll
        for (int sl = 0; sl < 2; ++sl)
#pragma unroll
            for (int g = 0; g < 4; ++g) vb[sl][g] = *(const bf16x8*)(p[sl][g] + ks * 512);
        const int ko = ks * 32 + q * 8;
#pragma unroll
        for (int mt = 0; mt < 2; ++mt) {
            bf16x8 ax = *(const bf16x8*)&Xs[(mt * 16 + lc) * SX + ko];
#pragma unroll
            for (int sl = 0; sl < 2; ++sl)
#pragma unroll
                for (int g = 0; g < 4; ++g)
                    acc[sl][g][mt] = mfma_bf16(ax, vb[sl][g], acc[sl][g][mt]);
        }
    }

#pragma unroll
    for (int sl = 0; sl < 2; ++sl) {
        const int jj = (2 * w + sl) * 16 + lc;
        float bias[4];
        bias[0] = b_ioux[jj]       + b_iouh[jj];
        bias[1] = b_ioux[256 + jj] + b_iouh[256 + jj];
        bias[2] = b_ioux[512 + jj] + b_iouh[512 + jj];
        bias[3] = b_fx[jj] + b_fh[jj];
#pragma unroll
        for (int g = 0; g < 4; ++g)
#pragma unroll
            for (int mt = 0; mt < 2; ++mt)
#pragma unroll
                for (int r = 0; r < 4; ++r) {
                    const int n = mt * 16 + q * 4 + r;
                    if (n < mcount)
                        xp[(size_t)(node0 + n) * 1024 + g * 256 + jj] = acc[sl][g][mt][r] + bias[g];
                }
    }
}

// 8-way column-split level kernel (d <= 12). blockIdx.y = colgroup cg in [0,8):
// the block computes 2 col-slices (s = 2cg + (w&1)). 8 waves = 2 slices x 4
// K-quarters (h-path ks pairs); K-quarter partials combine via LDS (stride-41
// f32, conflict-free, aliases staging after a barrier). With xpre non-null the
// x-GEMM is skipped: per-block stream = 64 KB wth + ~32 KB xpre (vs 295 KB).
__global__ __launch_bounds__(512, 4) void level_colsplit8(
    const float* __restrict__ x_in,
    const __bf16* __restrict__ wtx, const __bf16* __restrict__ wth,
    const float* __restrict__ b_ioux, const float* __restrict__ b_iouh,
    const float* __restrict__ b_fx, const float* __restrict__ b_fh,
    float* __restrict__ c, float* __restrict__ h,
    const float* __restrict__ xpre,    // null -> do x-GEMM in-kernel
    int start, int levsize)
{
    __shared__ __align__(16) unsigned char smem[71680];
    __bf16* Xs   = (__bf16*)smem;                  // NT*SX*2   = 20992 B
    __bf16* Hlr  = (__bf16*)(smem + 20992);        // 2*NT*SH*2 = 33792 B
    __bf16* Hsum = (__bf16*)(smem + 54784);        // NT*SH*2   = 16896 B

    const int tid = threadIdx.x;
    const int w = tid >> 6, l = tid & 63, lc = l & 15, q = l >> 4;
    const int s_loc = w & 1, kq = w >> 1;
    const int s = blockIdx.y * 2 + s_loc;          // col-slice 0..15
    const int tile0 = blockIdx.x * NT;
    const int node0 = start + tile0;
    const int mcount = min(NT, levsize - tile0);
    const int childbase = 2 * node0 + 1;

    if (xpre == nullptr) stage_x(x_in, Xs, node0, mcount);
    stage_h(h, Hlr, Hsum, childbase, mcount);
    __syncthreads();

    const f32x4 z4 = {0.f, 0.f, 0.f, 0.f};
    f32x4 aI[2], aO[2], aU[2], aL[2], aR[2];
#pragma unroll
    for (int mt = 0; mt < 2; ++mt) { aI[mt] = z4; aO[mt] = z4; aU[mt] = z4; aL[mt] = z4; aR[mt] = z4; }

    // ---- h-path GEMM, K-quarter kq: ks in {2kq, 2kq+1} ----
    {
        const __bf16* pi = wth + ((size_t)(s)      * NKH) * 512 + l * 8;
        const __bf16* po = wth + ((size_t)(16 + s) * NKH) * 512 + l * 8;
        const __bf16* pu = wth + ((size_t)(32 + s) * NKH) * 512 + l * 8;
        const __bf16* pf = wth + ((size_t)(48 + s) * NKH) * 512 + l * 8;
        for (int ks = 2 * kq; ks < 2 * kq + 2; ++ks) {
            bf16x8 vi = *(const bf16x8*)(pi + ks * 512);
            bf16x8 vo = *(const bf16x8*)(po + ks * 512);
            bf16x8 vu = *(const bf16x8*)(pu + ks * 512);
            bf16x8 vf = *(const bf16x8*)(pf + ks * 512);
            const int ko = ks * 32 + q * 8;
#pragma unroll
            for (int mt = 0; mt < 2; ++mt) {
                bf16x8 as = *(const bf16x8*)&Hsum[(mt * 16 + lc) * SH + ko];
                bf16x8 al = *(const bf16x8*)&Hlr[(mt * 16 + lc) * SH + ko];
                bf16x8 ar = *(const bf16x8*)&Hlr[(NT + mt * 16 + lc) * SH + ko];
                aI[mt] = mfma_bf16(as, vi, aI[mt]);
                aO[mt] = mfma_bf16(as, vo, aO[mt]);
                aU[mt] = mfma_bf16(as, vu, aU[mt]);
                aL[mt] = mfma_bf16(al, vf, aL[mt]);
                aR[mt] = mfma_bf16(ar, vf, aR[mt]);
            }
        }
    }
    // ---- x-path GEMM (fallback only), ks ranges {0-2,3-4,5-7,8-9} per kq ----
    if (xpre == nullptr) {
        const int xb[4] = {0, 3, 5, 8}, xe[4] = {3, 5, 8, 10};
        const __bf16* pi = wtx + ((size_t)(s)      * NKX) * 512 + l * 8;
        const __bf16* po = wtx + ((size_t)(16 + s) * NKX) * 512 + l * 8;
        const __bf16* pu = wtx + ((size_t)(32 + s) * NKX) * 512 + l * 8;
        const __bf16* pf = wtx + ((size_t)(48 + s) * NKX) * 512 + l * 8;
        for (int ks = xb[kq]; ks < xe[kq]; ++ks) {
            bf16x8 vi = *(const bf16x8*)(pi + ks * 512);
            bf16x8 vo = *(const bf16x8*)(po + ks * 512);
            bf16x8 vu = *(const bf16x8*)(pu + ks * 512);
            bf16x8 vf = *(const bf16x8*)(pf + ks * 512);
            const int ko = ks * 32 + q * 8;
#pragma unroll
            for (int mt = 0; mt < 2; ++mt) {
                bf16x8 ax = *(const bf16x8*)&Xs[(mt * 16 + lc) * SX + ko];
                aI[mt] = mfma_bf16(ax, vi, aI[mt]);
                aO[mt] = mfma_bf16(ax, vo, aO[mt]);
                aU[mt] = mfma_bf16(ax, vu, aU[mt]);
                aL[mt] = mfma_bf16(ax, vf, aL[mt]);
                aR[mt] = mfma_bf16(ax, vf, aR[mt]);
            }
        }
    }

    // ---- combine K-quarters via LDS (aliases staging; reads are done) ----
    __syncthreads();
    float* Rb = (float*)smem;   // 3 x 128 x RSTR f32 = 63 KB <= 70 KB
    if (kq != 0) {
        float* dst = Rb + (size_t)((kq - 1) * 128 + s_loc * 64 + l) * RSTR;
        int o = 0;
#pragma unroll
        for (int mt = 0; mt < 2; ++mt)
#pragma unroll
            for (int r = 0; r < 4; ++r) dst[o++] = aI[mt][r];
#pragma unroll
        for (int mt = 0; mt < 2; ++mt)
#pragma unroll
            for (int r = 0; r < 4; ++r) dst[o++] = aO[mt][r];
#pragma unroll
        for (int mt = 0; mt < 2; ++mt)
#pragma unroll
            for (int r = 0; r < 4; ++r) dst[o++] = aU[mt][r];
#pragma unroll
        for (int mt = 0; mt < 2; ++mt)
#pragma unroll
            for (int r = 0; r < 4; ++r) dst[o++] = aL[mt][r];
#pragma unroll
        for (int mt = 0; mt < 2; ++mt)
#pragma unroll
            for (int r = 0; r < 4; ++r) dst[o++] = aR[mt][r];
    }
    __syncthreads();
    if (kq == 0) {
#pragma unroll
        for (int p = 0; p < 3; ++p) {
            const float* src = Rb + (size_t)(p * 128 + s_loc * 64 + l) * RSTR;
            int o = 0;
#pragma unroll
            for (int mt = 0; mt < 2; ++mt)
#pragma unroll
                for (int r = 0; r < 4; ++r) aI[mt][r] += src[o++];
#pragma unroll
            for (int mt = 0; mt < 2; ++mt)
#pragma unroll
                for (int r = 0; r < 4; ++r) aO[mt][r] += src[o++];
#pragma unroll
            for (int mt = 0; mt < 2; ++mt)
#pragma unroll
                for (int r = 0; r < 4; ++r) aU[mt][r] += src[o++];
#pragma unroll
            for (int mt = 0; mt < 2; ++mt)
#pragma unroll
                for (int r = 0; r < 4; ++r) aL[mt][r] += src[o++];
#pragma unroll
            for (int mt = 0; mt < 2; ++mt)
#pragma unroll
                for (int r = 0; r < 4; ++r) aR[mt][r] += src[o++];
        }

        const int jj = s * 16 + lc;
        float bi = 0.f, bo = 0.f, bu = 0.f, bff = 0.f;
        if (xpre == nullptr) {
            bi  = b_ioux[jj]       + b_iouh[jj];
            bo  = b_ioux[256 + jj] + b_iouh[256 + jj];
            bu  = b_ioux[512 + jj] + b_iouh[512 + jj];
            bff = b_fx[jj] + b_fh[jj];
        }
#pragma unroll
        for (int mt = 0; mt < 2; ++mt) {
#pragma unroll
            for (int r = 0; r < 4; ++r) {
                const int n = mt * 16 + q * 4 + r;
                if (n >= mcount) continue;
                float ai = aI[mt][r], ao = aO[mt][r], au = aU[mt][r];
                float al_ = aL[mt][r], ar_ = aR[mt][r];
                if (xpre != nullptr) {
                    const float* xr = xpre + (size_t)(node0 + n) * 1024;
                    ai += xr[jj]; ao += xr[256 + jj]; au += xr[512 + jj];
                    const float xf = xr[768 + jj];
                    al_ += xf; ar_ += xf;
                } else {
                    ai += bi; ao += bo; au += bu; al_ += bff; ar_ += bff;
                }
                const float iv = sigmoidf_(ai);
                const float ov = sigmoidf_(ao);
                const float uv = tanhfast_(au);
                const float fl = sigmoidf_(al_);
                const float fr = sigmoidf_(ar_);
                const float cl = c[(size_t)(childbase + 2 * n) * MEM + jj];
                const float cr = c[(size_t)(childbase + 2 * n + 1) * MEM + jj];
                const float cn = iv * uv + fl * cl + fr * cr;
                const float hn = ov * tanhfast_(cn);
                c[(size_t)(node0 + n) * MEM + jj] = cn;
                h[(size_t)(node0 + n) * MEM + jj] = hn;
            }
        }
    }
}

extern "C" void kernel_launch(void* const* d_in, const int* in_sizes, int n_in,
                              void* d_out, int out_size, void* d_ws, size_t ws_size,
                              hipStream_t stream) {
    const float* inputs = (const float*)d_in[0];
    const float* W_ioux = (const float*)d_in[1];
    const float* b_ioux = (const float*)d_in[2];
    const float* W_iouh = (const float*)d_in[3];
    const float* b_iouh = (const float*)d_in[4];
    const float* W_fx   = (const float*)d_in[5];
    const float* b_fx   = (const float*)d_in[6];
    const float* W_fh   = (const float*)d_in[7];
    const float* b_fh   = (const float*)d_in[8];

    float* out = (float*)d_out;
    float* c = out;
    float* h = out + (size_t)NNODES * MEM;

    __bf16* wtx = (__bf16*)d_ws;
    __bf16* wth = wtx + WTXF_ELEMS;

    const size_t wbytes = (size_t)(WTXF_ELEMS + WTHF_ELEMS) * sizeof(__bf16);  // 1.18 MB
    const size_t xpre_bytes = (size_t)XPRE_NODES * 1024 * sizeof(float);       // 33.5 MB
    float* xpre = nullptr;
    if (ws_size >= wbytes + xpre_bytes)
        xpre = (float*)((char*)d_ws + wbytes);

    {
        int total = WTXF_ELEMS + WTHF_ELEMS;
        hipLaunchKernelGGL(prep_weights, dim3((total + 255) / 256), dim3(256),
                           0, stream, W_ioux, W_fx, W_iouh, W_fh, (__bf16*)d_ws);
    }
    // Upfront x-path for all d <= 12 nodes (tree-independent)
    if (xpre != nullptr)
        hipLaunchKernelGGL(xpre_gemm, dim3((XPRE_NODES + NT - 1) / NT), dim3(512), 0, stream,
                           inputs, wtx, b_ioux, b_iouh, b_fx, b_fh, xpre, XPRE_NODES);

    // d = 15 (leaves): x-GEMM only, 1024 blocks
    hipLaunchKernelGGL((level_mfma<true, 4>), dim3(1024), dim3(512), 0, stream,
                       inputs, wtx, wth, b_ioux, b_iouh, b_fx, b_fh, c, h,
                       (1 << 15) - 1, 1 << 15);
    // d = 14, 13: full tile kernel (GPU saturated by block count)
    hipLaunchKernelGGL((level_mfma<false, 2>), dim3(512), dim3(512), 0, stream,
                       inputs, wtx, wth, b_ioux, b_iouh, b_fx, b_fh, c, h,
                       (1 << 14) - 1, 1 << 14);
    hipLaunchKernelGGL((level_mfma<false, 2>), dim3(256), dim3(512), 0, stream,
                       inputs, wtx, wth, b_ioux, b_iouh, b_fx, b_fh, c, h,
                       (1 << 13) - 1, 1 << 13);
    // d = 12..0: 8-way column-split kernel (h-GEMM only when xpre available)
    for (int d = 12; d >= 0; --d) {
        int start = (1 << d) - 1;
        int sz = 1 << d;
        dim3 grid((sz + NT - 1) / NT, 8);
        hipLaunchKernelGGL(level_colsplit8, grid, dim3(512), 0, stream,
                           inputs, wtx, wth, b_ioux, b_iouh, b_fx, b_fh, c, h,
                           xpre, start, sz);
    }
}

// Round 8
// 445.160 us; speedup vs baseline: 1.2106x; 1.2106x over previous
//
#include <hip/hip_runtime.h>
#include <math.h>

#define IN_DIM 300
#define MEM 256
#define DEPTH 15
#define NNODES ((1 << (DEPTH + 1)) - 1)   // 65535
#define KX 320     // x-GEMM K (300 padded)
#define KH 256     // h-GEMM K
#define NKX 10     // KX/32
#define NKH 8      // KH/32
#define SX 328     // LDS row stride bf16
#define SH 264     // LDS row stride bf16
#define NT 32      // nodes per tile (2 x 16-row MFMA sub-tiles)
#define RSTR 41    // reduce-buffer lane stride f32 (odd -> conflict-free)
#define XPRE_NODES 8191   // nodes 0..8190 = levels d <= 12

typedef __attribute__((ext_vector_type(8))) __bf16 bf16x8;
typedef __attribute__((ext_vector_type(4))) float f32x4;

__device__ __forceinline__ float sigmoidf_(float x) { return 1.0f / (1.0f + __expf(-x)); }
__device__ __forceinline__ float tanhfast_(float x) {
    return 1.0f - 2.0f / (__expf(2.0f * x) + 1.0f);
}
__device__ __forceinline__ f32x4 mfma_bf16(bf16x8 a, bf16x8 b, f32x4 acc) {
    return __builtin_amdgcn_mfma_f32_16x16x32_bf16(a, b, acc, 0, 0, 0);
}

// Fragment-linear B layout: elem(cb, ks, lane, e) at ((cb*NK + ks)*64 + lane)*8 + e,
// holding W[col = cb*16 + (lane&15)][k = ks*32 + (lane>>4)*8 + e].
#define WTXF_ELEMS (64 * NKX * 512)   // 327680  (cols 0..767 = W_ioux, 768..1023 = W_fx)
#define WTHF_ELEMS (64 * NKH * 512)   // 262144  (cols 0..767 = W_iouh, 768..1023 = W_fh)

__global__ void prep_weights(const float* __restrict__ W_ioux, const float* __restrict__ W_fx,
                             const float* __restrict__ W_iouh, const float* __restrict__ W_fh,
                             __bf16* __restrict__ ws) {
    int idx = blockIdx.x * 256 + threadIdx.x;
    if (idx < WTXF_ELEMS) {
        int e = idx & 7, ln = (idx >> 3) & 63;
        int r = idx >> 9;             // 0..639
        int ks = r % NKX, cb = r / NKX;
        int col = cb * 16 + (ln & 15);
        int k = ks * 32 + (ln >> 4) * 8 + e;
        float v = 0.f;
        if (k < IN_DIM)
            v = (col < 768) ? W_ioux[col * IN_DIM + k] : W_fx[(col - 768) * IN_DIM + k];
        ws[idx] = (__bf16)v;
    } else if (idx < WTXF_ELEMS + WTHF_ELEMS) {
        int t = idx - WTXF_ELEMS;
        int e = t & 7, ln = (t >> 3) & 63;
        int r = t >> 9;               // 0..511
        int ks = r & 7, cb = r >> 3;
        int col = cb * 16 + (ln & 15);
        int k = ks * 32 + (ln >> 4) * 8 + e;
        float v = (col < 768) ? W_iouh[col * MEM + k] : W_fh[(col - 768) * MEM + k];
        ws[WTXF_ELEMS + t] = (__bf16)v;
    }
}

// ---- shared staging helpers (512 threads) ----
__device__ __forceinline__ void stage_x(const float* __restrict__ x_in, __bf16* Xs,
                                        int node0, int mcount) {
    for (int t = threadIdx.x; t < NT * (KX / 8); t += 512) {
        int m = t / (KX / 8), kc = t - m * (KX / 8), k = kc * 8;
        float4 v0 = {0.f, 0.f, 0.f, 0.f}, v1 = {0.f, 0.f, 0.f, 0.f};
        if (m < mcount) {
            const float* row = x_in + (size_t)(node0 + m) * IN_DIM;
            if (k + 8 <= IN_DIM) { v0 = *(const float4*)(row + k); v1 = *(const float4*)(row + k + 4); }
            else if (k == 296)   { v0 = *(const float4*)(row + k); }   // 296..299 valid
        }
        bf16x8 pk;
        pk[0] = (__bf16)v0.x; pk[1] = (__bf16)v0.y; pk[2] = (__bf16)v0.z; pk[3] = (__bf16)v0.w;
        pk[4] = (__bf16)v1.x; pk[5] = (__bf16)v1.y; pk[6] = (__bf16)v1.z; pk[7] = (__bf16)v1.w;
        *(bf16x8*)&Xs[m * SX + k] = pk;
    }
}

__device__ __forceinline__ void stage_h(const float* __restrict__ h, __bf16* Hlr, __bf16* Hsum,
                                        int childbase, int mcount) {
    for (int t = threadIdx.x; t < NT * (KH / 8); t += 512) {
        int m = t >> 5, kc = t & 31, k = kc * 8;
        float4 l0 = {0.f,0.f,0.f,0.f}, l1 = l0, r0 = l0, r1 = l0;
        if (m < mcount) {
            const float4* lp = (const float4*)(h + (size_t)(childbase + 2 * m) * MEM + k);
            const float4* rp = (const float4*)(h + (size_t)(childbase + 2 * m + 1) * MEM + k);
            l0 = lp[0]; l1 = lp[1]; r0 = rp[0]; r1 = rp[1];
        }
        bf16x8 pl, pr, ps;
        pl[0]=(__bf16)l0.x; pl[1]=(__bf16)l0.y; pl[2]=(__bf16)l0.z; pl[3]=(__bf16)l0.w;
        pl[4]=(__bf16)l1.x; pl[5]=(__bf16)l1.y; pl[6]=(__bf16)l1.z; pl[7]=(__bf16)l1.w;
        pr[0]=(__bf16)r0.x; pr[1]=(__bf16)r0.y; pr[2]=(__bf16)r0.z; pr[3]=(__bf16)r0.w;
        pr[4]=(__bf16)r1.x; pr[5]=(__bf16)r1.y; pr[6]=(__bf16)r1.z; pr[7]=(__bf16)r1.w;
        ps[0]=(__bf16)(l0.x+r0.x); ps[1]=(__bf16)(l0.y+r0.y);
        ps[2]=(__bf16)(l0.z+r0.z); ps[3]=(__bf16)(l0.w+r0.w);
        ps[4]=(__bf16)(l1.x+r1.x); ps[5]=(__bf16)(l1.y+r1.y);
        ps[6]=(__bf16)(l1.z+r1.z); ps[7]=(__bf16)(l1.w+r1.w);
        *(bf16x8*)&Hlr[m * SH + k] = pl;
        *(bf16x8*)&Hlr[(NT + m) * SH + k] = pr;
        *(bf16x8*)&Hsum[m * SH + k] = ps;
    }
}

// 512-thread / 8-wave tile. Wave w owns TWO 16-col slices (s0=2w, s1=2w+1) of
// every gate group -> 8 B-streams, acc = 80 f32. 8-wave block = 2 waves/SIMD
// -> 256-reg budget: no spill (16-wave blocks cap at 128 regs and spilled).
template <bool LEAF>
__device__ __forceinline__ void tile_body(
    const float* __restrict__ x_in,
    const __bf16* __restrict__ wtx, const __bf16* __restrict__ wth,
    const float* __restrict__ b_ioux, const float* __restrict__ b_iouh,
    const float* __restrict__ b_fx, const float* __restrict__ b_fh,
    float* __restrict__ c, float* __restrict__ h,
    int node0, int mcount, __bf16* Xs, __bf16* Hlr, __bf16* Hsum)
{
    const int tid = threadIdx.x;               // 0..511
    const int w = tid >> 6, l = tid & 63, lc = l & 15, q = l >> 4;
    const int childbase = 2 * node0 + 1;

    stage_x(x_in, Xs, node0, mcount);
    if constexpr (!LEAF) stage_h(h, Hlr, Hsum, childbase, mcount);
    __syncthreads();

    const f32x4 z4 = {0.f, 0.f, 0.f, 0.f};
    f32x4 aI[2][2], aO[2][2], aU[2][2], aL[2][2], aR[2][2];
#pragma unroll
    for (int s = 0; s < 2; ++s)
#pragma unroll
        for (int mt = 0; mt < 2; ++mt) {
            aI[s][mt] = z4; aO[s][mt] = z4; aU[s][mt] = z4;
            if constexpr (!LEAF) { aL[s][mt] = z4; aR[s][mt] = z4; }
        }

    const int s0 = 2 * w, s1 = 2 * w + 1;

    if constexpr (!LEAF) {
        const __bf16* pi0 = wth + ((size_t)(s0)      * NKH) * 512 + l * 8;
        const __bf16* pi1 = wth + ((size_t)(s1)      * NKH) * 512 + l * 8;
        const __bf16* po0 = wth + ((size_t)(16 + s0) * NKH) * 512 + l * 8;
        const __bf16* po1 = wth + ((size_t)(16 + s1) * NKH) * 512 + l * 8;
        const __bf16* pu0 = wth + ((size_t)(32 + s0) * NKH) * 512 + l * 8;
        const __bf16* pu1 = wth + ((size_t)(32 + s1) * NKH) * 512 + l * 8;
        const __bf16* pf0 = wth + ((size_t)(48 + s0) * NKH) * 512 + l * 8;
        const __bf16* pf1 = wth + ((size_t)(48 + s1) * NKH) * 512 + l * 8;
        for (int ks = 0; ks < NKH; ++ks) {
            bf16x8 vi0 = *(const bf16x8*)(pi0 + ks * 512);
            bf16x8 vi1 = *(const bf16x8*)(pi1 + ks * 512);
            bf16x8 vo0 = *(const bf16x8*)(po0 + ks * 512);
            bf16x8 vo1 = *(const bf16x8*)(po1 + ks * 512);
            bf16x8 vu0 = *(const bf16x8*)(pu0 + ks * 512);
            bf16x8 vu1 = *(const bf16x8*)(pu1 + ks * 512);
            bf16x8 vf0 = *(const bf16x8*)(pf0 + ks * 512);
            bf16x8 vf1 = *(const bf16x8*)(pf1 + ks * 512);
            const int ko = ks * 32 + q * 8;
#pragma unroll
            for (int mt = 0; mt < 2; ++mt) {
                bf16x8 as = *(const bf16x8*)&Hsum[(mt * 16 + lc) * SH + ko];
                bf16x8 al = *(const bf16x8*)&Hlr[(mt * 16 + lc) * SH + ko];
                bf16x8 ar = *(const bf16x8*)&Hlr[(NT + mt * 16 + lc) * SH + ko];
                aI[0][mt] = mfma_bf16(as, vi0, aI[0][mt]);
                aI[1][mt] = mfma_bf16(as, vi1, aI[1][mt]);
                aO[0][mt] = mfma_bf16(as, vo0, aO[0][mt]);
                aO[1][mt] = mfma_bf16(as, vo1, aO[1][mt]);
                aU[0][mt] = mfma_bf16(as, vu0, aU[0][mt]);
                aU[1][mt] = mfma_bf16(as, vu1, aU[1][mt]);
                aL[0][mt] = mfma_bf16(al, vf0, aL[0][mt]);
                aL[1][mt] = mfma_bf16(al, vf1, aL[1][mt]);
                aR[0][mt] = mfma_bf16(ar, vf0, aR[0][mt]);
                aR[1][mt] = mfma_bf16(ar, vf1, aR[1][mt]);
            }
        }
    }

    {
        const __bf16* pi0 = wtx + ((size_t)(s0)      * NKX) * 512 + l * 8;
        const __bf16* pi1 = wtx + ((size_t)(s1)      * NKX) * 512 + l * 8;
        const __bf16* po0 = wtx + ((size_t)(16 + s0) * NKX) * 512 + l * 8;
        const __bf16* po1 = wtx + ((size_t)(16 + s1) * NKX) * 512 + l * 8;
        const __bf16* pu0 = wtx + ((size_t)(32 + s0) * NKX) * 512 + l * 8;
        const __bf16* pu1 = wtx + ((size_t)(32 + s1) * NKX) * 512 + l * 8;
        const __bf16* pf0 = wtx + ((size_t)(48 + s0) * NKX) * 512 + l * 8;
        const __bf16* pf1 = wtx + ((size_t)(48 + s1) * NKX) * 512 + l * 8;
        for (int ks = 0; ks < NKX; ++ks) {
            bf16x8 vi0 = *(const bf16x8*)(pi0 + ks * 512);
            bf16x8 vi1 = *(const bf16x8*)(pi1 + ks * 512);
            bf16x8 vo0 = *(const bf16x8*)(po0 + ks * 512);
            bf16x8 vo1 = *(const bf16x8*)(po1 + ks * 512);
            bf16x8 vu0 = *(const bf16x8*)(pu0 + ks * 512);
            bf16x8 vu1 = *(const bf16x8*)(pu1 + ks * 512);
            bf16x8 vf0, vf1;
            if constexpr (!LEAF) {
                vf0 = *(const bf16x8*)(pf0 + ks * 512);
                vf1 = *(const bf16x8*)(pf1 + ks * 512);
            }
            const int ko = ks * 32 + q * 8;
#pragma unroll
            for (int mt = 0; mt < 2; ++mt) {
                bf16x8 ax = *(const bf16x8*)&Xs[(mt * 16 + lc) * SX + ko];
                aI[0][mt] = mfma_bf16(ax, vi0, aI[0][mt]);
                aI[1][mt] = mfma_bf16(ax, vi1, aI[1][mt]);
                aO[0][mt] = mfma_bf16(ax, vo0, aO[0][mt]);
                aO[1][mt] = mfma_bf16(ax, vo1, aO[1][mt]);
                aU[0][mt] = mfma_bf16(ax, vu0, aU[0][mt]);
                aU[1][mt] = mfma_bf16(ax, vu1, aU[1][mt]);
                if constexpr (!LEAF) {
                    aL[0][mt] = mfma_bf16(ax, vf0, aL[0][mt]);
                    aR[0][mt] = mfma_bf16(ax, vf0, aR[0][mt]);
                    aL[1][mt] = mfma_bf16(ax, vf1, aL[1][mt]);
                    aR[1][mt] = mfma_bf16(ax, vf1, aR[1][mt]);
                }
            }
        }
    }

#pragma unroll
    for (int s = 0; s < 2; ++s) {
        const int jj = (2 * w + s) * 16 + lc;
        const float bi = b_ioux[jj]       + b_iouh[jj];
        const float bo = b_ioux[256 + jj] + b_iouh[256 + jj];
        const float bu = b_ioux[512 + jj] + b_iouh[512 + jj];
        float bff = 0.f;
        if constexpr (!LEAF) bff = b_fx[jj] + b_fh[jj];
#pragma unroll
        for (int mt = 0; mt < 2; ++mt) {
#pragma unroll
            for (int r = 0; r < 4; ++r) {
                const int n = mt * 16 + q * 4 + r;
                const float iv = sigmoidf_(aI[s][mt][r] + bi);
                const float ov = sigmoidf_(aO[s][mt][r] + bo);
                const float uv = tanhfast_(aU[s][mt][r] + bu);
                float cn;
                if constexpr (!LEAF) {
                    const float fl = sigmoidf_(aL[s][mt][r] + bff);
                    const float fr = sigmoidf_(aR[s][mt][r] + bff);
                    float cl = 0.f, cr = 0.f;
                    if (n < mcount) {
                        cl = c[(size_t)(childbase + 2 * n) * MEM + jj];
                        cr = c[(size_t)(childbase + 2 * n + 1) * MEM + jj];
                    }
                    cn = iv * uv + fl * cl + fr * cr;
                } else {
                    cn = iv * uv;
                }
                const float hn = ov * tanhfast_(cn);
                if (n < mcount) {
                    c[(size_t)(node0 + n) * MEM + jj] = cn;
                    h[(size_t)(node0 + n) * MEM + jj] = hn;
                }
            }
        }
    }
}

template <bool LEAF, int MINW>
__global__ __launch_bounds__(512, MINW) void level_mfma(
    const float* __restrict__ x_in,
    const __bf16* __restrict__ wtx, const __bf16* __restrict__ wth,
    const float* __restrict__ b_ioux, const float* __restrict__ b_iouh,
    const float* __restrict__ b_fx, const float* __restrict__ b_fh,
    float* __restrict__ c, float* __restrict__ h,
    int start, int levsize)
{
    __shared__ __align__(16) __bf16 Xs[NT * SX];
    __shared__ __align__(16) __bf16 Hlr[LEAF ? 8 : 2 * NT * SH];
    __shared__ __align__(16) __bf16 Hsum[LEAF ? 8 : NT * SH];
    const int tile0 = blockIdx.x * NT;
    tile_body<LEAF>(x_in, wtx, wth, b_ioux, b_iouh, b_fx, b_fh, c, h,
                    start + tile0, min(NT, levsize - tile0), Xs, Hlr, Hsum);
}

// Upfront x-path GEMM for nodes 0..nnodes-1 (tree-independent): writes
// xp[node][1024] = {iou_x + b_ioux + b_iouh (cols 0..767), fx + b_fx + b_fh
// (cols 768..1023)} in f32. Small levels then skip the x-GEMM entirely.
__global__ __launch_bounds__(512, 2) void xpre_gemm(
    const float* __restrict__ x_in, const __bf16* __restrict__ wtx,
    const float* __restrict__ b_ioux, const float* __restrict__ b_iouh,
    const float* __restrict__ b_fx, const float* __restrict__ b_fh,
    float* __restrict__ xp, int nnodes)
{
    __shared__ __align__(16) __bf16 Xs[NT * SX];
    const int tid = threadIdx.x;
    const int w = tid >> 6, l = tid & 63, lc = l & 15, q = l >> 4;
    const int node0 = blockIdx.x * NT;
    const int mcount = min(NT, nnodes - node0);
    stage_x(x_in, Xs, node0, mcount);
    __syncthreads();

    const f32x4 z4 = {0.f, 0.f, 0.f, 0.f};
    f32x4 acc[2][4][2];
#pragma unroll
    for (int sl = 0; sl < 2; ++sl)
#pragma unroll
        for (int g = 0; g < 4; ++g)
#pragma unroll
            for (int mt = 0; mt < 2; ++mt) acc[sl][g][mt] = z4;

    const __bf16* p[2][4];
#pragma unroll
    for (int sl = 0; sl < 2; ++sl) {
        const int s_ = 2 * w + sl;
        p[sl][0] = wtx + ((size_t)(s_)      * NKX) * 512 + l * 8;
        p[sl][1] = wtx + ((size_t)(16 + s_) * NKX) * 512 + l * 8;
        p[sl][2] = wtx + ((size_t)(32 + s_) * NKX) * 512 + l * 8;
        p[sl][3] = wtx + ((size_t)(48 + s_) * NKX) * 512 + l * 8;
    }
    for (int ks = 0; ks < NKX; ++ks) {
        bf16x8 vb[2][4];
#pragma unroll
        for (int sl = 0; sl < 2; ++sl)
#pragma unroll
            for (int g = 0; g < 4; ++g) vb[sl][g] = *(const bf16x8*)(p[sl][g] + ks * 512);
        const int ko = ks * 32 + q * 8;
#pragma unroll
        for (int mt = 0; mt < 2; ++mt) {
            bf16x8 ax = *(const bf16x8*)&Xs[(mt * 16 + lc) * SX + ko];
#pragma unroll
            for (int sl = 0; sl < 2; ++sl)
#pragma unroll
                for (int g = 0; g < 4; ++g)
                    acc[sl][g][mt] = mfma_bf16(ax, vb[sl][g], acc[sl][g][mt]);
        }
    }

#pragma unroll
    for (int sl = 0; sl < 2; ++sl) {
        const int jj = (2 * w + sl) * 16 + lc;
        float bias[4];
        bias[0] = b_ioux[jj]       + b_iouh[jj];
        bias[1] = b_ioux[256 + jj] + b_iouh[256 + jj];
        bias[2] = b_ioux[512 + jj] + b_iouh[512 + jj];
        bias[3] = b_fx[jj] + b_fh[jj];
#pragma unroll
        for (int g = 0; g < 4; ++g)
#pragma unroll
            for (int mt = 0; mt < 2; ++mt)
#pragma unroll
                for (int r = 0; r < 4; ++r) {
                    const int n = mt * 16 + q * 4 + r;
                    if (n < mcount)
                        xp[(size_t)(node0 + n) * 1024 + g * 256 + jj] = acc[sl][g][mt][r] + bias[g];
                }
    }
}

// 8-way column-split level kernel (d <= 12). blockIdx.y = colgroup cg in [0,8):
// the block computes 2 col-slices (s = 2cg + (w&1)). 8 waves = 2 slices x 4
// K-quarters (h-path ks pairs); K-quarter partials combine via LDS (stride-41
// f32, conflict-free, aliases staging after a barrier). With xpre non-null the
// x-GEMM is skipped: per-block stream = 64 KB wth + ~32 KB xpre (vs 295 KB).
// MINW=2 (NOT 4): 8-wave block at 2 waves/SIMD -> 256-reg budget. MINW=4
// capped regs at 128 and spilled 27 MB of scratch per d12 dispatch (round 7).
__global__ __launch_bounds__(512, 2) void level_colsplit8(
    const float* __restrict__ x_in,
    const __bf16* __restrict__ wtx, const __bf16* __restrict__ wth,
    const float* __restrict__ b_ioux, const float* __restrict__ b_iouh,
    const float* __restrict__ b_fx, const float* __restrict__ b_fh,
    float* __restrict__ c, float* __restrict__ h,
    const float* __restrict__ xpre,    // null -> do x-GEMM in-kernel
    int start, int levsize)
{
    __shared__ __align__(16) unsigned char smem[71680];
    __bf16* Xs   = (__bf16*)smem;                  // NT*SX*2   = 20992 B
    __bf16* Hlr  = (__bf16*)(smem + 20992);        // 2*NT*SH*2 = 33792 B
    __bf16* Hsum = (__bf16*)(smem + 54784);        // NT*SH*2   = 16896 B

    const int tid = threadIdx.x;
    const int w = tid >> 6, l = tid & 63, lc = l & 15, q = l >> 4;
    const int s_loc = w & 1, kq = w >> 1;
    const int s = blockIdx.y * 2 + s_loc;          // col-slice 0..15
    const int tile0 = blockIdx.x * NT;
    const int node0 = start + tile0;
    const int mcount = min(NT, levsize - tile0);
    const int childbase = 2 * node0 + 1;

    if (xpre == nullptr) stage_x(x_in, Xs, node0, mcount);
    stage_h(h, Hlr, Hsum, childbase, mcount);
    __syncthreads();

    const f32x4 z4 = {0.f, 0.f, 0.f, 0.f};
    f32x4 aI[2], aO[2], aU[2], aL[2], aR[2];
#pragma unroll
    for (int mt = 0; mt < 2; ++mt) { aI[mt] = z4; aO[mt] = z4; aU[mt] = z4; aL[mt] = z4; aR[mt] = z4; }

    // ---- h-path GEMM, K-quarter kq: ks in {2kq, 2kq+1} ----
    {
        const __bf16* pi = wth + ((size_t)(s)      * NKH) * 512 + l * 8;
        const __bf16* po = wth + ((size_t)(16 + s) * NKH) * 512 + l * 8;
        const __bf16* pu = wth + ((size_t)(32 + s) * NKH) * 512 + l * 8;
        const __bf16* pf = wth + ((size_t)(48 + s) * NKH) * 512 + l * 8;
        for (int ks = 2 * kq; ks < 2 * kq + 2; ++ks) {
            bf16x8 vi = *(const bf16x8*)(pi + ks * 512);
            bf16x8 vo = *(const bf16x8*)(po + ks * 512);
            bf16x8 vu = *(const bf16x8*)(pu + ks * 512);
            bf16x8 vf = *(const bf16x8*)(pf + ks * 512);
            const int ko = ks * 32 + q * 8;
#pragma unroll
            for (int mt = 0; mt < 2; ++mt) {
                bf16x8 as = *(const bf16x8*)&Hsum[(mt * 16 + lc) * SH + ko];
                bf16x8 al = *(const bf16x8*)&Hlr[(mt * 16 + lc) * SH + ko];
                bf16x8 ar = *(const bf16x8*)&Hlr[(NT + mt * 16 + lc) * SH + ko];
                aI[mt] = mfma_bf16(as, vi, aI[mt]);
                aO[mt] = mfma_bf16(as, vo, aO[mt]);
                aU[mt] = mfma_bf16(as, vu, aU[mt]);
                aL[mt] = mfma_bf16(al, vf, aL[mt]);
                aR[mt] = mfma_bf16(ar, vf, aR[mt]);
            }
        }
    }
    // ---- x-path GEMM (fallback only), ks ranges {0-2,3-4,5-7,8-9} per kq ----
    if (xpre == nullptr) {
        const int xb[4] = {0, 3, 5, 8}, xe[4] = {3, 5, 8, 10};
        const __bf16* pi = wtx + ((size_t)(s)      * NKX) * 512 + l * 8;
        const __bf16* po = wtx + ((size_t)(16 + s) * NKX) * 512 + l * 8;
        const __bf16* pu = wtx + ((size_t)(32 + s) * NKX) * 512 + l * 8;
        const __bf16* pf = wtx + ((size_t)(48 + s) * NKX) * 512 + l * 8;
        for (int ks = xb[kq]; ks < xe[kq]; ++ks) {
            bf16x8 vi = *(const bf16x8*)(pi + ks * 512);
            bf16x8 vo = *(const bf16x8*)(po + ks * 512);
            bf16x8 vu = *(const bf16x8*)(pu + ks * 512);
            bf16x8 vf = *(const bf16x8*)(pf + ks * 512);
            const int ko = ks * 32 + q * 8;
#pragma unroll
            for (int mt = 0; mt < 2; ++mt) {
                bf16x8 ax = *(const bf16x8*)&Xs[(mt * 16 + lc) * SX + ko];
                aI[mt] = mfma_bf16(ax, vi, aI[mt]);
                aO[mt] = mfma_bf16(ax, vo, aO[mt]);
                aU[mt] = mfma_bf16(ax, vu, aU[mt]);
                aL[mt] = mfma_bf16(ax, vf, aL[mt]);
                aR[mt] = mfma_bf16(ax, vf, aR[mt]);
            }
        }
    }

    // ---- combine K-quarters via LDS (aliases staging; reads are done) ----
    __syncthreads();
    float* Rb = (float*)smem;   // 3 x 128 x RSTR f32 = 63 KB <= 70 KB
    if (kq != 0) {
        float* dst = Rb + (size_t)((kq - 1) * 128 + s_loc * 64 + l) * RSTR;
        int o = 0;
#pragma unroll
        for (int mt = 0; mt < 2; ++mt)
#pragma unroll
            for (int r = 0; r < 4; ++r) dst[o++] = aI[mt][r];
#pragma unroll
        for (int mt = 0; mt < 2; ++mt)
#pragma unroll
            for (int r = 0; r < 4; ++r) dst[o++] = aO[mt][r];
#pragma unroll
        for (int mt = 0; mt < 2; ++mt)
#pragma unroll
            for (int r = 0; r < 4; ++r) dst[o++] = aU[mt][r];
#pragma unroll
        for (int mt = 0; mt < 2; ++mt)
#pragma unroll
            for (int r = 0; r < 4; ++r) dst[o++] = aL[mt][r];
#pragma unroll
        for (int mt = 0; mt < 2; ++mt)
#pragma unroll
            for (int r = 0; r < 4; ++r) dst[o++] = aR[mt][r];
    }
    __syncthreads();
    if (kq == 0) {
#pragma unroll
        for (int p = 0; p < 3; ++p) {
            const float* src = Rb + (size_t)(p * 128 + s_loc * 64 + l) * RSTR;
            int o = 0;
#pragma unroll
            for (int mt = 0; mt < 2; ++mt)
#pragma unroll
                for (int r = 0; r < 4; ++r) aI[mt][r] += src[o++];
#pragma unroll
            for (int mt = 0; mt < 2; ++mt)
#pragma unroll
                for (int r = 0; r < 4; ++r) aO[mt][r] += src[o++];
#pragma unroll
            for (int mt = 0; mt < 2; ++mt)
#pragma unroll
                for (int r = 0; r < 4; ++r) aU[mt][r] += src[o++];
#pragma unroll
            for (int mt = 0; mt < 2; ++mt)
#pragma unroll
                for (int r = 0; r < 4; ++r) aL[mt][r] += src[o++];
#pragma unroll
            for (int mt = 0; mt < 2; ++mt)
#pragma unroll
                for (int r = 0; r < 4; ++r) aR[mt][r] += src[o++];
        }

        const int jj = s * 16 + lc;
        float bi = 0.f, bo = 0.f, bu = 0.f, bff = 0.f;
        if (xpre == nullptr) {
            bi  = b_ioux[jj]       + b_iouh[jj];
            bo  = b_ioux[256 + jj] + b_iouh[256 + jj];
            bu  = b_ioux[512 + jj] + b_iouh[512 + jj];
            bff = b_fx[jj] + b_fh[jj];
        }
#pragma unroll
        for (int mt = 0; mt < 2; ++mt) {
#pragma unroll
            for (int r = 0; r < 4; ++r) {
                const int n = mt * 16 + q * 4 + r;
                if (n >= mcount) continue;
                float ai = aI[mt][r], ao = aO[mt][r], au = aU[mt][r];
                float al_ = aL[mt][r], ar_ = aR[mt][r];
                if (xpre != nullptr) {
                    const float* xr = xpre + (size_t)(node0 + n) * 1024;
                    ai += xr[jj]; ao += xr[256 + jj]; au += xr[512 + jj];
                    const float xf = xr[768 + jj];
                    al_ += xf; ar_ += xf;
                } else {
                    ai += bi; ao += bo; au += bu; al_ += bff; ar_ += bff;
                }
                const float iv = sigmoidf_(ai);
                const float ov = sigmoidf_(ao);
                const float uv = tanhfast_(au);
                const float fl = sigmoidf_(al_);
                const float fr = sigmoidf_(ar_);
                const float cl = c[(size_t)(childbase + 2 * n) * MEM + jj];
                const float cr = c[(size_t)(childbase + 2 * n + 1) * MEM + jj];
                const float cn = iv * uv + fl * cl + fr * cr;
                const float hn = ov * tanhfast_(cn);
                c[(size_t)(node0 + n) * MEM + jj] = cn;
                h[(size_t)(node0 + n) * MEM + jj] = hn;
            }
        }
    }
}

extern "C" void kernel_launch(void* const* d_in, const int* in_sizes, int n_in,
                              void* d_out, int out_size, void* d_ws, size_t ws_size,
                              hipStream_t stream) {
    const float* inputs = (const float*)d_in[0];
    const float* W_ioux = (const float*)d_in[1];
    const float* b_ioux = (const float*)d_in[2];
    const float* W_iouh = (const float*)d_in[3];
    const float* b_iouh = (const float*)d_in[4];
    const float* W_fx   = (const float*)d_in[5];
    const float* b_fx   = (const float*)d_in[6];
    const float* W_fh   = (const float*)d_in[7];
    const float* b_fh   = (const float*)d_in[8];

    float* out = (float*)d_out;
    float* c = out;
    float* h = out + (size_t)NNODES * MEM;

    __bf16* wtx = (__bf16*)d_ws;
    __bf16* wth = wtx + WTXF_ELEMS;

    const size_t wbytes = (size_t)(WTXF_ELEMS + WTHF_ELEMS) * sizeof(__bf16);  // 1.18 MB
    const size_t xpre_bytes = (size_t)XPRE_NODES * 1024 * sizeof(float);       // 33.5 MB
    float* xpre = nullptr;
    if (ws_size >= wbytes + xpre_bytes)
        xpre = (float*)((char*)d_ws + wbytes);

    {
        int total = WTXF_ELEMS + WTHF_ELEMS;
        hipLaunchKernelGGL(prep_weights, dim3((total + 255) / 256), dim3(256),
                           0, stream, W_ioux, W_fx, W_iouh, W_fh, (__bf16*)d_ws);
    }
    // Upfront x-path for all d <= 12 nodes (tree-independent)
    if (xpre != nullptr)
        hipLaunchKernelGGL(xpre_gemm, dim3((XPRE_NODES + NT - 1) / NT), dim3(512), 0, stream,
                           inputs, wtx, b_ioux, b_iouh, b_fx, b_fh, xpre, XPRE_NODES);

    // d = 15 (leaves): x-GEMM only, 1024 blocks
    hipLaunchKernelGGL((level_mfma<true, 4>), dim3(1024), dim3(512), 0, stream,
                       inputs, wtx, wth, b_ioux, b_iouh, b_fx, b_fh, c, h,
                       (1 << 15) - 1, 1 << 15);
    // d = 14, 13: full tile kernel (GPU saturated by block count)
    hipLaunchKernelGGL((level_mfma<false, 2>), dim3(512), dim3(512), 0, stream,
                       inputs, wtx, wth, b_ioux, b_iouh, b_fx, b_fh, c, h,
                       (1 << 14) - 1, 1 << 14);
    hipLaunchKernelGGL((level_mfma<false, 2>), dim3(256), dim3(512), 0, stream,
                       inputs, wtx, wth, b_ioux, b_iouh, b_fx, b_fh, c, h,
                       (1 << 13) - 1, 1 << 13);
    // d = 12..0: 8-way column-split kernel (h-GEMM only when xpre available)
    for (int d = 12; d >= 0; --d) {
        int start = (1 << d) - 1;
        int sz = 1 << d;
        dim3 grid((sz + NT - 1) / NT, 8);
        hipLaunchKernelGGL(level_colsplit8, grid, dim3(512), 0, stream,
                           inputs, wtx, wth, b_ioux, b_iouh, b_fx, b_fh, c, h,
                           xpre, start, sz);
    }
}